// Round 2
// baseline (198.179 us; speedup 1.0000x reference)
//
#include <hip/hip_runtime.h>
#include <hip/hip_bf16.h>
#include <stdint.h>

#define B_ 4
#define P_ 256
#define S_ 4096
#define D_ 1024
#define H_ 16
#define HD_ 64

typedef __attribute__((ext_vector_type(8))) short short8;
typedef __attribute__((ext_vector_type(4))) short short4v;
typedef __attribute__((ext_vector_type(4))) float f32x4;

__device__ __forceinline__ float b2f(short s) {
  return __uint_as_float(((unsigned)(unsigned short)s) << 16);
}
__device__ __forceinline__ short f2bf(float f) {
  unsigned u = __float_as_uint(f);
  unsigned r = (u + 0x7fffu + ((u >> 16) & 1u)) >> 16;
  return (short)(unsigned short)r;
}

// ---------------------------------------------------------------------------
// prep: convert byte_hidden + 4 weights to bf16; LayerNorm(patch_emb) -> bf16
// grid: 8192 (X) + 2048 (weights) + 1024 (LN rows) = 11264 blocks x 256
// ---------------------------------------------------------------------------
__global__ __launch_bounds__(256) void prep_kernel(
    const float* __restrict__ xbytes, const float* __restrict__ pe,
    const float* __restrict__ gamma, const float* __restrict__ beta,
    const float* __restrict__ wq, const float* __restrict__ wk,
    const float* __restrict__ wv, const float* __restrict__ wo,
    short* __restrict__ Xb, short* __restrict__ wqb, short* __restrict__ wkb,
    short* __restrict__ wvb, short* __restrict__ wob, short* __restrict__ qx)
{
  const int bid = blockIdx.x;
  const int tid = threadIdx.x;
  if (bid < 8192) {
    const size_t base = (size_t)bid * 2048 + (size_t)tid * 8;
    const float4 f0 = *(const float4*)(xbytes + base);
    const float4 f1 = *(const float4*)(xbytes + base + 4);
    short8 o;
    o[0] = f2bf(f0.x); o[1] = f2bf(f0.y); o[2] = f2bf(f0.z); o[3] = f2bf(f0.w);
    o[4] = f2bf(f1.x); o[5] = f2bf(f1.y); o[6] = f2bf(f1.z); o[7] = f2bf(f1.w);
    *(short8*)(Xb + base) = o;
  } else if (bid < 8192 + 2048) {
    const int r = bid - 8192;
    const int wi = r >> 9;
    const size_t base = (size_t)(r & 511) * 2048 + (size_t)tid * 8;
    const float* src; short* dst;
    if (wi == 0)      { src = wq; dst = wqb; }
    else if (wi == 1) { src = wk; dst = wkb; }
    else if (wi == 2) { src = wv; dst = wvb; }
    else              { src = wo; dst = wob; }
    const float4 f0 = *(const float4*)(src + base);
    const float4 f1 = *(const float4*)(src + base + 4);
    short8 o;
    o[0] = f2bf(f0.x); o[1] = f2bf(f0.y); o[2] = f2bf(f0.z); o[3] = f2bf(f0.w);
    o[4] = f2bf(f1.x); o[5] = f2bf(f1.y); o[6] = f2bf(f1.z); o[7] = f2bf(f1.w);
    *(short8*)(dst + base) = o;
  } else {
    // LayerNorm: one block per row of patch_embeddings (B*P = 1024 rows)
    const int row = bid - 10240;
    const int c = tid * 4;
    const float4 x = *(const float4*)(pe + (size_t)row * D_ + c);
    float s1 = x.x + x.y + x.z + x.w;
    float s2 = x.x * x.x + x.y * x.y + x.z * x.z + x.w * x.w;
    #pragma unroll
    for (int off = 32; off >= 1; off >>= 1) {
      s1 += __shfl_xor(s1, off, 64);
      s2 += __shfl_xor(s2, off, 64);
    }
    __shared__ float red[8];
    const int wid = tid >> 6, lane = tid & 63;
    if (lane == 0) { red[wid] = s1; red[4 + wid] = s2; }
    __syncthreads();
    s1 = red[0] + red[1] + red[2] + red[3];
    s2 = red[4] + red[5] + red[6] + red[7];
    const float mu = s1 * (1.0f / D_);
    const float var = s2 * (1.0f / D_) - mu * mu;
    const float rs = rsqrtf(var + 1e-5f);
    const float4 g = *(const float4*)(gamma + c);
    const float4 bt = *(const float4*)(beta + c);
    short4v o;
    o[0] = f2bf((x.x - mu) * rs * g.x + bt.x);
    o[1] = f2bf((x.y - mu) * rs * g.y + bt.y);
    o[2] = f2bf((x.z - mu) * rs * g.z + bt.z);
    o[3] = f2bf((x.w - mu) * rs * g.w + bt.w);
    *(short4v*)(qx + (size_t)row * D_ + c) = o;
  }
}

// ---------------------------------------------------------------------------
// GEMM core: C[M,N] = A[M,K] * W[N,K]^T, bf16 in, f32 acc, 128x128 tile,
// BK=64, 4 waves (2x2), each wave 64x64 = 4x4 frags of mfma_f32_16x16x32_bf16.
// global_load_lds width=16, 2-barrier K-loop (m97 structure).
// ---------------------------------------------------------------------------
#define BM 128
#define BN 128
#define BK 64

__device__ __forceinline__ void gemm_core(
    const short* __restrict__ A, const short* __restrict__ W,
    int mt, int nt, int Kd, f32x4 acc[4][4], short* As, short* Bs)
{
  const int tid = threadIdx.x;
  const int wid = tid >> 6, lane = tid & 63;
  const int lr = lane & 15, lk = lane >> 4;
  const int seg_row = lane >> 3;            // 0..7 rows within a 1KB segment
  const int seg_col = (lane & 7) * 8;       // element col within 64-wide row
  const int wr = wid >> 1, wc = wid & 1;

  for (int kt = 0; kt < Kd; kt += BK) {
    __syncthreads();
    #pragma unroll
    for (int j = 0; j < 4; ++j) {
      const int s = wid * 4 + j;            // segment 0..15 (8 rows each)
      const size_t arow = (size_t)(mt * BM + s * 8 + seg_row);
      const size_t brow = (size_t)(nt * BN + s * 8 + seg_row);
      __builtin_amdgcn_global_load_lds(
          (const __attribute__((address_space(1))) void*)(A + arow * Kd + kt + seg_col),
          (__attribute__((address_space(3))) void*)(As + s * 512), 16, 0, 0);
      __builtin_amdgcn_global_load_lds(
          (const __attribute__((address_space(1))) void*)(W + brow * Kd + kt + seg_col),
          (__attribute__((address_space(3))) void*)(Bs + s * 512), 16, 0, 0);
    }
    asm volatile("s_waitcnt vmcnt(0)" ::: "memory");
    __syncthreads();
    #pragma unroll
    for (int ks = 0; ks < 2; ++ks) {
      short8 a[4], bfr[4];
      #pragma unroll
      for (int m = 0; m < 4; ++m)
        a[m] = *(const short8*)(As + (wr * 64 + m * 16 + lr) * BK + ks * 32 + lk * 8);
      #pragma unroll
      for (int n = 0; n < 4; ++n)
        bfr[n] = *(const short8*)(Bs + (wc * 64 + n * 16 + lr) * BK + ks * 32 + lk * 8);
      #pragma unroll
      for (int m = 0; m < 4; ++m)
        #pragma unroll
        for (int n = 0; n < 4; ++n)
          acc[m][n] = __builtin_amdgcn_mfma_f32_16x16x32_bf16(a[m], bfr[n], acc[m][n], 0, 0, 0);
    }
  }
}

// K,V,Q projections in one launch, XCD-swizzled.
// logical work w in [0,2048): mt = w>>4, proj = (w>>3)&1 (0=K,1=V), nt = w&7
//   -> 16 consecutive work-ids share one Xb A-panel (both K and V proj).
// w in [2048,2112): Q-proj, mt = (w-2048)>>3, nt = (w-2048)&7.
// physical bid -> work id: u = (bid&7)*264 + (bid>>3)  (2112 = 8*264, bijective)
// so each XCD's L2 sees a contiguous chunk of work -> A-panels L2-resident.
__global__ __launch_bounds__(256) void gemm_kvq(
    const short* __restrict__ Xb, const short* __restrict__ qx,
    const short* __restrict__ wqb, const short* __restrict__ wkb,
    const short* __restrict__ wvb,
    const float* __restrict__ b_q, const float* __restrict__ b_k,
    const float* __restrict__ b_v,
    short* __restrict__ Ko, short* __restrict__ Vo, short* __restrict__ Qo)
{
  __shared__ __align__(16) short As[BM * BK];
  __shared__ __align__(16) short Bs[BN * BK];
  const int bid = blockIdx.x;
  const int u = (bid & 7) * 264 + (bid >> 3);   // XCD-contiguous work id
  const short* A; const short* W; const float* bias; short* C;
  int mt, nt;
  if (u < 2048) {
    mt = u >> 4; nt = u & 7;
    if (u & 8) { A = Xb; W = wvb; bias = b_v; C = Vo; }
    else       { A = Xb; W = wkb; bias = b_k; C = Ko; }
  } else {
    const int q = u - 2048;
    mt = q >> 3; nt = q & 7;
    A = qx; W = wqb; bias = b_q; C = Qo;
  }

  f32x4 acc[4][4] = {};
  gemm_core(A, W, mt, nt, D_, acc, As, Bs);

  const int lane = threadIdx.x & 63;
  const int wid = threadIdx.x >> 6;
  const int wr = wid >> 1, wc = wid & 1;
  const int lr = lane & 15, lq = lane >> 4;
  #pragma unroll
  for (int n = 0; n < 4; ++n) {
    const int col = nt * BN + wc * 64 + n * 16 + lr;
    const float bv = bias[col];
    #pragma unroll
    for (int m = 0; m < 4; ++m) {
      const int row0 = mt * BM + wr * 64 + m * 16 + lq * 4;
      #pragma unroll
      for (int i = 0; i < 4; ++i)
        C[(size_t)(row0 + i) * D_ + col] = f2bf(acc[m][n][i] + bv);
    }
  }
}

// O projection + bias + residual, fp32 out. 64 blocks.
__global__ __launch_bounds__(256) void gemm_o(
    const short* __restrict__ AO, const short* __restrict__ wob,
    const float* __restrict__ b_o, const float* __restrict__ pe,
    float* __restrict__ out)
{
  __shared__ __align__(16) short As[BM * BK];
  __shared__ __align__(16) short Bs[BN * BK];
  const int bid = blockIdx.x;
  const int mt = bid >> 3, nt = bid & 7;

  f32x4 acc[4][4] = {};
  gemm_core(AO, wob, mt, nt, D_, acc, As, Bs);

  const int lane = threadIdx.x & 63;
  const int wid = threadIdx.x >> 6;
  const int wr = wid >> 1, wc = wid & 1;
  const int lr = lane & 15, lq = lane >> 4;
  #pragma unroll
  for (int n = 0; n < 4; ++n) {
    const int col = nt * BN + wc * 64 + n * 16 + lr;
    const float bv = b_o[col];
    #pragma unroll
    for (int m = 0; m < 4; ++m) {
      const int row0 = mt * BM + wr * 64 + m * 16 + lq * 4;
      #pragma unroll
      for (int i = 0; i < 4; ++i) {
        const size_t idx = (size_t)(row0 + i) * D_ + col;
        out[idx] = acc[m][n][i] + bv + pe[idx];
      }
    }
  }
}

// ---------------------------------------------------------------------------
// Attention: 1 block per (b,p), 4 waves x 4 heads. lane = (tq 0..15, dg 0..3).
// Online softmax over 16-wide chunks of the span; matches reference semantics
// including the all-masked/invalid-span uniform fallback.
// ---------------------------------------------------------------------------
__global__ __launch_bounds__(256) void attn_kernel(
    const short* __restrict__ Q, const short* __restrict__ K,
    const short* __restrict__ V, const int* __restrict__ pos,
    const float* __restrict__ mask, short* __restrict__ O)
{
  const int bp = blockIdx.x;
  const int b = bp >> 8;
  const int tid = threadIdx.x;
  const int wid = tid >> 6, lane = tid & 63;
  const int tq = lane & 15, dg = lane >> 4;

  // int64-vs-int32 layout probe: patch 0's end >= 1 always; int64 high word = 0
  const bool is64 = (pos[1] == 0);
  const int start = is64 ? pos[4 * bp]     : pos[2 * bp];
  const int end   = is64 ? pos[4 * bp + 2] : pos[2 * bp + 1];
  const bool valid = (start < S_) && (end <= S_) && (start < end);
  const int lo = valid ? (start < 0 ? 0 : start) : 0;
  const int hi = valid ? end : 0;

  for (int hh = 0; hh < 4; ++hh) {
    const int h = wid * 4 + hh;
    const short* qp = Q + (size_t)bp * D_ + h * HD_ + dg * 16;
    const short8 q0 = *(const short8*)qp;
    const short8 q1 = *(const short8*)(qp + 8);
    float qf[16];
    #pragma unroll
    for (int j = 0; j < 8; ++j) { qf[j] = b2f(q0[j]); qf[8 + j] = b2f(q1[j]); }

    float mrun = -3.0e38f, denom = 0.f, oacc = 0.f;
    for (int c0 = lo; c0 < hi; c0 += 16) {
      const int t = c0 + tq;
      const bool ok = (t < hi) && (mask[(size_t)b * S_ + t] != 0.f);
      float part = 0.f;
      if (ok) {
        const short* kp = K + ((size_t)b * S_ + t) * D_ + h * HD_ + dg * 16;
        const short8 k0 = *(const short8*)kp;
        const short8 k1 = *(const short8*)(kp + 8);
        #pragma unroll
        for (int j = 0; j < 8; ++j) part += qf[j] * b2f(k0[j]);
        #pragma unroll
        for (int j = 0; j < 8; ++j) part += qf[8 + j] * b2f(k1[j]);
      }
      part += __shfl_xor(part, 16, 64);
      part += __shfl_xor(part, 32, 64);
      const float sc = ok ? part * 0.125f : -3.0e38f;
      float cm = sc;
      cm = fmaxf(cm, __shfl_xor(cm, 1, 64));
      cm = fmaxf(cm, __shfl_xor(cm, 2, 64));
      cm = fmaxf(cm, __shfl_xor(cm, 4, 64));
      cm = fmaxf(cm, __shfl_xor(cm, 8, 64));
      const float nm = fmaxf(mrun, cm);
      if (nm <= -1.0e38f) continue;        // nothing allowed so far
      const float r = __expf(mrun - nm);   // mrun=-3e38 -> 0
      const float w = ok ? __expf(sc - nm) : 0.f;
      float ws = w;
      ws += __shfl_xor(ws, 1, 64);
      ws += __shfl_xor(ws, 2, 64);
      ws += __shfl_xor(ws, 4, 64);
      ws += __shfl_xor(ws, 8, 64);
      denom = denom * r + ws;
      oacc *= r;
      #pragma unroll
      for (int k2 = 0; k2 < 16; ++k2) {
        const float wk = __shfl(w, k2, 64);   // uniform across wave
        if (wk > 0.f) {
          oacc += wk * b2f(V[((size_t)b * S_ + c0 + k2) * D_ + h * HD_ + lane]);
        }
      }
      mrun = nm;
    }
    float res;
    if (denom > 0.f) {
      res = oacc / denom;
    } else {
      // reference: softmax over all -1e9 -> uniform over ALL S positions
      float sum = 0.f;
      for (int s0 = 0; s0 < S_; ++s0)
        sum += b2f(V[((size_t)b * S_ + s0) * D_ + h * HD_ + lane]);
      res = sum * (1.0f / S_);
    }
    O[(size_t)bp * D_ + h * HD_ + lane] = f2bf(res);
  }
}

// ---------------------------------------------------------------------------
extern "C" void kernel_launch(void* const* d_in, const int* in_sizes, int n_in,
                              void* d_out, int out_size, void* d_ws, size_t ws_size,
                              hipStream_t stream)
{
  const float* pe    = (const float*)d_in[0];
  const float* xby   = (const float*)d_in[1];
  const int*   pos   = (const int*)d_in[2];
  const float* mask  = (const float*)d_in[3];
  const float* gamma = (const float*)d_in[4];
  const float* beta  = (const float*)d_in[5];
  const float* w_q   = (const float*)d_in[6];
  const float* b_q   = (const float*)d_in[7];
  const float* w_k   = (const float*)d_in[8];
  const float* b_k   = (const float*)d_in[9];
  const float* w_v   = (const float*)d_in[10];
  const float* b_v   = (const float*)d_in[11];
  const float* w_o   = (const float*)d_in[12];
  const float* b_o   = (const float*)d_in[13];

  char* ws = (char*)d_ws;
  short* Xb  = (short*)(ws);                 // 32 MB: byte_hidden bf16 [16384][1024]
  short* Ko  = (short*)(ws + 33554432);      // 32 MB: K bf16
  short* Vo  = (short*)(ws + 67108864);      // 32 MB: V bf16
  short* wqb = (short*)(ws + 100663296);     // 2 MB each: bf16 weights
  short* wkb = (short*)(ws + 102760448);
  short* wvb = (short*)(ws + 104857600);
  short* wob = (short*)(ws + 106954752);
  short* qx  = (short*)(ws + 109051904);     // 2 MB: LN(patch_emb) bf16
  short* Qo  = (short*)(ws + 111149056);     // 2 MB: Q bf16
  short* AO  = (short*)(ws + 113246208);     // 2 MB: attention out bf16
  (void)in_sizes; (void)n_in; (void)out_size; (void)ws_size;

  prep_kernel<<<11264, 256, 0, stream>>>(xby, pe, gamma, beta, w_q, w_k, w_v, w_o,
                                         Xb, wqb, wkb, wvb, wob, qx);
  gemm_kvq<<<2112, 256, 0, stream>>>(Xb, qx, wqb, wkb, wvb, b_q, b_k, b_v, Ko, Vo, Qo);
  attn_kernel<<<1024, 256, 0, stream>>>(Qo, Ko, Vo, pos, mask, AO);
  gemm_o<<<64, 256, 0, stream>>>(AO, wob, b_o, pe, (float*)d_out);
}

// Round 3
// 181.450 us; speedup vs baseline: 1.0922x; 1.0922x over previous
//
#include <hip/hip_runtime.h>
#include <hip/hip_bf16.h>
#include <stdint.h>

#define B_ 4
#define P_ 256
#define S_ 4096
#define D_ 1024
#define H_ 16
#define HD_ 64

typedef __attribute__((ext_vector_type(8))) short short8;
typedef __attribute__((ext_vector_type(4))) short short4v;
typedef __attribute__((ext_vector_type(4))) float f32x4;

__device__ __forceinline__ float b2f(short s) {
  return __uint_as_float(((unsigned)(unsigned short)s) << 16);
}
__device__ __forceinline__ short f2bf(float f) {
  unsigned u = __float_as_uint(f);
  unsigned r = (u + 0x7fffu + ((u >> 16) & 1u)) >> 16;
  return (short)(unsigned short)r;
}

#define BARR asm volatile("s_barrier" ::: "memory")
#define LGKM0 asm volatile("s_waitcnt lgkmcnt(0)" ::: "memory")
#define VMC4 asm volatile("s_waitcnt vmcnt(4)" ::: "memory")
#define VMC0 asm volatile("s_waitcnt vmcnt(0)" ::: "memory")

// ---------------------------------------------------------------------------
// prep: convert byte_hidden + 4 weights to bf16; LayerNorm(patch_emb) -> bf16
// ---------------------------------------------------------------------------
__global__ __launch_bounds__(256) void prep_kernel(
    const float* __restrict__ xbytes, const float* __restrict__ pe,
    const float* __restrict__ gamma, const float* __restrict__ beta,
    const float* __restrict__ wq, const float* __restrict__ wk,
    const float* __restrict__ wv, const float* __restrict__ wo,
    short* __restrict__ Xb, short* __restrict__ wqb, short* __restrict__ wkb,
    short* __restrict__ wvb, short* __restrict__ wob, short* __restrict__ qx)
{
  const int bid = blockIdx.x;
  const int tid = threadIdx.x;
  if (bid < 8192) {
    const size_t base = (size_t)bid * 2048 + (size_t)tid * 8;
    const float4 f0 = *(const float4*)(xbytes + base);
    const float4 f1 = *(const float4*)(xbytes + base + 4);
    short8 o;
    o[0] = f2bf(f0.x); o[1] = f2bf(f0.y); o[2] = f2bf(f0.z); o[3] = f2bf(f0.w);
    o[4] = f2bf(f1.x); o[5] = f2bf(f1.y); o[6] = f2bf(f1.z); o[7] = f2bf(f1.w);
    *(short8*)(Xb + base) = o;
  } else if (bid < 8192 + 2048) {
    const int r = bid - 8192;
    const int wi = r >> 9;
    const size_t base = (size_t)(r & 511) * 2048 + (size_t)tid * 8;
    const float* src; short* dst;
    if (wi == 0)      { src = wq; dst = wqb; }
    else if (wi == 1) { src = wk; dst = wkb; }
    else if (wi == 2) { src = wv; dst = wvb; }
    else              { src = wo; dst = wob; }
    const float4 f0 = *(const float4*)(src + base);
    const float4 f1 = *(const float4*)(src + base + 4);
    short8 o;
    o[0] = f2bf(f0.x); o[1] = f2bf(f0.y); o[2] = f2bf(f0.z); o[3] = f2bf(f0.w);
    o[4] = f2bf(f1.x); o[5] = f2bf(f1.y); o[6] = f2bf(f1.z); o[7] = f2bf(f1.w);
    *(short8*)(dst + base) = o;
  } else {
    const int row = bid - 10240;
    const int c = tid * 4;
    const float4 x = *(const float4*)(pe + (size_t)row * D_ + c);
    float s1 = x.x + x.y + x.z + x.w;
    float s2 = x.x * x.x + x.y * x.y + x.z * x.z + x.w * x.w;
    #pragma unroll
    for (int off = 32; off >= 1; off >>= 1) {
      s1 += __shfl_xor(s1, off, 64);
      s2 += __shfl_xor(s2, off, 64);
    }
    __shared__ float red[8];
    const int wid = tid >> 6, lane = tid & 63;
    if (lane == 0) { red[wid] = s1; red[4 + wid] = s2; }
    __syncthreads();
    s1 = red[0] + red[1] + red[2] + red[3];
    s2 = red[4] + red[5] + red[6] + red[7];
    const float mu = s1 * (1.0f / D_);
    const float var = s2 * (1.0f / D_) - mu * mu;
    const float rs = rsqrtf(var + 1e-5f);
    const float4 g = *(const float4*)(gamma + c);
    const float4 bt = *(const float4*)(beta + c);
    short4v o;
    o[0] = f2bf((x.x - mu) * rs * g.x + bt.x);
    o[1] = f2bf((x.y - mu) * rs * g.y + bt.y);
    o[2] = f2bf((x.z - mu) * rs * g.z + bt.z);
    o[3] = f2bf((x.w - mu) * rs * g.w + bt.w);
    *(short4v*)(qx + (size_t)row * D_ + c) = o;
  }
}

// ---------------------------------------------------------------------------
// 256x256-tile 8-wave phase-pipelined GEMM (T1+T2+T3+T4+T5):
//   C[M,N] = A[M,K] * W[N,K]^T, bf16 in, f32 acc.
// BK=32, 2-tile LDS double-buffer (64 KB), counted vmcnt(4) (never 0 in loop),
// per-phase: reads -> barrier -> lgkmcnt(0) -> setprio(1) -> 16 MFMA ->
// setprio(0) -> barrier. Stages issued only in reg-only phases; each buffer's
// reads fully drained (lgkmcnt(0)) one barrier before any DMA targets it.
// LDS swizzle: slot' = slot ^ ((row>>1)&3)  (involution on both sides).
// ---------------------------------------------------------------------------
__device__ __forceinline__ void stage_tile(
    const short* agp0, const short* agp1, const short* bgp0, const short* bgp1,
    int T, short* AsF, short* BsF, int buf, int ldst)
{
  const int go = T * 32;
  const int lb = buf * 8192 + ldst;
  __builtin_amdgcn_global_load_lds(
      (const __attribute__((address_space(1))) void*)(agp0 + go),
      (__attribute__((address_space(3))) void*)(AsF + lb), 16, 0, 0);
  __builtin_amdgcn_global_load_lds(
      (const __attribute__((address_space(1))) void*)(agp1 + go),
      (__attribute__((address_space(3))) void*)(AsF + lb + 4096), 16, 0, 0);
  __builtin_amdgcn_global_load_lds(
      (const __attribute__((address_space(1))) void*)(bgp0 + go),
      (__attribute__((address_space(3))) void*)(BsF + lb), 16, 0, 0);
  __builtin_amdgcn_global_load_lds(
      (const __attribute__((address_space(1))) void*)(bgp1 + go),
      (__attribute__((address_space(3))) void*)(BsF + lb + 4096), 16, 0, 0);
}

template <int MB>
__device__ __forceinline__ void mfma_half(const short8 (&af)[8], const short8 (&bfv)[4],
                                          f32x4 (&acc)[8][4])
{
  #pragma unroll
  for (int m = 0; m < 4; ++m)
    #pragma unroll
    for (int n = 0; n < 4; ++n)
      acc[MB + m][n] = __builtin_amdgcn_mfma_f32_16x16x32_bf16(af[MB + m], bfv[n], acc[MB + m][n], 0, 0, 0);
}

// bids: 528 blocks. u = XCD-contiguous work id. u<512: K/V (mt=u>>3, proj=(u>>2)&1,
// nt=u&3 -> 8 works share one 512KB A-panel per XCD). u>=512: Q (mt=(u-512)>>2).
__global__ __launch_bounds__(512, 2) void gemm_kvq256(
    const short* __restrict__ Xb, const short* __restrict__ qx,
    const short* __restrict__ wqb, const short* __restrict__ wkb,
    const short* __restrict__ wvb,
    const float* __restrict__ b_q, const float* __restrict__ b_k,
    const float* __restrict__ b_v,
    short* __restrict__ Ko, short* __restrict__ Vo, short* __restrict__ Qo)
{
  __shared__ __align__(16) short AsF[16384];   // 2 bufs x 256 rows x 32 cols
  __shared__ __align__(16) short BsF[16384];

  const int tid = threadIdx.x;
  const int wid = tid >> 6, lane = tid & 63;
  const int wr = wid >> 2, wc = wid & 3;
  const int lr = lane & 15, lk = lane >> 4;

  const int bid = blockIdx.x;
  const int u = (bid & 7) * 66 + (bid >> 3);
  const short* A; const short* W; const float* bias; short* C;
  int mt, nt;
  if (u < 512) {
    mt = u >> 3; nt = u & 3;
    if ((u >> 2) & 1) { A = Xb; W = wvb; bias = b_v; C = Vo; }
    else              { A = Xb; W = wkb; bias = b_k; C = Ko; }
  } else {
    const int q = u - 512; mt = q >> 2; nt = q & 3;
    A = qx; W = wqb; bias = b_q; C = Qo;
  }

  // staging per-thread constants: chunk row = tid>>2 (0..127), swizzled slot
  const int str = tid >> 2;
  const int ssw = ((tid & 3) ^ ((tid >> 3) & 3)) * 8;
  const short* agp0 = A + (size_t)(mt * 256 + str) * D_ + ssw;
  const short* agp1 = A + (size_t)(mt * 256 + 128 + str) * D_ + ssw;
  const short* bgp0 = W + (size_t)(nt * 256 + str) * D_ + ssw;
  const short* bgp1 = W + (size_t)(nt * 256 + 128 + str) * D_ + ssw;
  const int ldst = wid * 512;

  // fragment read offsets (elements), swizzle slot^((row>>1)&3)
  int offA[8], offB[4];
  #pragma unroll
  for (int m = 0; m < 8; ++m) {
    const int rA = wr * 128 + m * 16 + lr;
    offA[m] = rA * 32 + ((lk ^ ((rA >> 1) & 3)) * 8);
  }
  #pragma unroll
  for (int n = 0; n < 4; ++n) {
    const int rB = wc * 64 + n * 16 + lr;
    offB[n] = rB * 32 + ((lk ^ ((rB >> 1) & 3)) * 8);
  }

  f32x4 acc[8][4] = {};
  short8 af[8], bfv[4];

  // prologue: tiles 0,1 -> bufs 0,1; publish tile 0
  stage_tile(agp0, agp1, bgp0, bgp1, 0, AsF, BsF, 0, ldst);
  stage_tile(agp0, agp1, bgp0, bgp1, 1, AsF, BsF, 1, ldst);
  VMC4; BARR;

  for (int it = 0; it < 16; ++it) {
    // ---- ph1: read buf0 frags; MFMA m0-3 (tile 2it)
    #pragma unroll
    for (int m = 0; m < 8; ++m) af[m] = *(const short8*)(AsF + offA[m]);
    #pragma unroll
    for (int n = 0; n < 4; ++n) bfv[n] = *(const short8*)(BsF + offB[n]);
    BARR; LGKM0;
    __builtin_amdgcn_s_setprio(1);
    mfma_half<0>(af, bfv, acc);
    __builtin_amdgcn_s_setprio(0);
    BARR;
    // ---- ph2: stage tile 2it+2 -> buf0; drain tile 2it+1; MFMA m4-7
    if (it < 15) {
      stage_tile(agp0, agp1, bgp0, bgp1, 2 * it + 2, AsF, BsF, 0, ldst);
      VMC4;
    } else {
      VMC0;   // final: force tile 31 landed for ph3
    }
    BARR;
    __builtin_amdgcn_s_setprio(1);
    mfma_half<4>(af, bfv, acc);
    __builtin_amdgcn_s_setprio(0);
    BARR;
    // ---- ph3: read buf1 frags; MFMA m0-3 (tile 2it+1)
    #pragma unroll
    for (int m = 0; m < 8; ++m) af[m] = *(const short8*)(AsF + 8192 + offA[m]);
    #pragma unroll
    for (int n = 0; n < 4; ++n) bfv[n] = *(const short8*)(BsF + 8192 + offB[n]);
    BARR; LGKM0;
    __builtin_amdgcn_s_setprio(1);
    mfma_half<0>(af, bfv, acc);
    __builtin_amdgcn_s_setprio(0);
    BARR;
    // ---- ph4: stage tile 2it+3 -> buf1; drain tile 2it+2; MFMA m4-7
    if (it < 15)
      stage_tile(agp0, agp1, bgp0, bgp1, 2 * it + 3, AsF, BsF, 1, ldst);
    VMC4;
    BARR;
    __builtin_amdgcn_s_setprio(1);
    mfma_half<4>(af, bfv, acc);
    __builtin_amdgcn_s_setprio(0);
    BARR;
  }

  // epilogue: C-write with bias, bf16
  #pragma unroll
  for (int n = 0; n < 4; ++n) {
    const int col = nt * 256 + wc * 64 + n * 16 + lr;
    const float bv = bias[col];
    #pragma unroll
    for (int m = 0; m < 8; ++m) {
      const int row0 = mt * 256 + wr * 128 + m * 16 + lk * 4;
      #pragma unroll
      for (int i = 0; i < 4; ++i)
        C[(size_t)(row0 + i) * D_ + col] = f2bf(acc[m][n][i] + bv);
    }
  }
}

// ---------------------------------------------------------------------------
// old 128x128 m97-structure core (kept for gemm_o: 64 blocks, K=1024)
// ---------------------------------------------------------------------------
#define BM 128
#define BN 128
#define BK 64

__device__ __forceinline__ void gemm_core(
    const short* __restrict__ A, const short* __restrict__ W,
    int mt, int nt, int Kd, f32x4 acc[4][4], short* As, short* Bs)
{
  const int tid = threadIdx.x;
  const int wid = tid >> 6, lane = tid & 63;
  const int lr = lane & 15, lk = lane >> 4;
  const int seg_row = lane >> 3;
  const int seg_col = (lane & 7) * 8;
  const int wr = wid >> 1, wc = wid & 1;

  for (int kt = 0; kt < Kd; kt += BK) {
    __syncthreads();
    #pragma unroll
    for (int j = 0; j < 4; ++j) {
      const int s = wid * 4 + j;
      const size_t arow = (size_t)(mt * BM + s * 8 + seg_row);
      const size_t brow = (size_t)(nt * BN + s * 8 + seg_row);
      __builtin_amdgcn_global_load_lds(
          (const __attribute__((address_space(1))) void*)(A + arow * Kd + kt + seg_col),
          (__attribute__((address_space(3))) void*)(As + s * 512), 16, 0, 0);
      __builtin_amdgcn_global_load_lds(
          (const __attribute__((address_space(1))) void*)(W + brow * Kd + kt + seg_col),
          (__attribute__((address_space(3))) void*)(Bs + s * 512), 16, 0, 0);
    }
    asm volatile("s_waitcnt vmcnt(0)" ::: "memory");
    __syncthreads();
    #pragma unroll
    for (int ks = 0; ks < 2; ++ks) {
      short8 a[4], bfr[4];
      #pragma unroll
      for (int m = 0; m < 4; ++m)
        a[m] = *(const short8*)(As + (wr * 64 + m * 16 + lr) * BK + ks * 32 + lk * 8);
      #pragma unroll
      for (int n = 0; n < 4; ++n)
        bfr[n] = *(const short8*)(Bs + (wc * 64 + n * 16 + lr) * BK + ks * 32 + lk * 8);
      #pragma unroll
      for (int m = 0; m < 4; ++m)
        #pragma unroll
        for (int n = 0; n < 4; ++n)
          acc[m][n] = __builtin_amdgcn_mfma_f32_16x16x32_bf16(a[m], bfr[n], acc[m][n], 0, 0, 0);
    }
  }
}

__global__ __launch_bounds__(256) void gemm_o(
    const short* __restrict__ AO, const short* __restrict__ wob,
    const float* __restrict__ b_o, const float* __restrict__ pe,
    float* __restrict__ out)
{
  __shared__ __align__(16) short As[BM * BK];
  __shared__ __align__(16) short Bs[BN * BK];
  const int bid = blockIdx.x;
  const int mt = bid >> 3, nt = bid & 7;

  f32x4 acc[4][4] = {};
  gemm_core(AO, wob, mt, nt, D_, acc, As, Bs);

  const int lane = threadIdx.x & 63;
  const int wid = threadIdx.x >> 6;
  const int wr = wid >> 1, wc = wid & 1;
  const int lr = lane & 15, lq = lane >> 4;
  #pragma unroll
  for (int n = 0; n < 4; ++n) {
    const int col = nt * BN + wc * 64 + n * 16 + lr;
    const float bv = b_o[col];
    #pragma unroll
    for (int m = 0; m < 4; ++m) {
      const int row0 = mt * BM + wr * 64 + m * 16 + lq * 4;
      #pragma unroll
      for (int i = 0; i < 4; ++i) {
        const size_t idx = (size_t)(row0 + i) * D_ + col;
        out[idx] = acc[m][n][i] + bv + pe[idx];
      }
    }
  }
}

// ---------------------------------------------------------------------------
// Attention: 1 block per (b,p), 4 waves x 4 heads.
// ---------------------------------------------------------------------------
__global__ __launch_bounds__(256) void attn_kernel(
    const short* __restrict__ Q, const short* __restrict__ K,
    const short* __restrict__ V, const int* __restrict__ pos,
    const float* __restrict__ mask, short* __restrict__ O)
{
  const int bp = blockIdx.x;
  const int b = bp >> 8;
  const int tid = threadIdx.x;
  const int wid = tid >> 6, lane = tid & 63;
  const int tq = lane & 15, dg = lane >> 4;

  const bool is64 = (pos[1] == 0);
  const int start = is64 ? pos[4 * bp]     : pos[2 * bp];
  const int end   = is64 ? pos[4 * bp + 2] : pos[2 * bp + 1];
  const bool valid = (start < S_) && (end <= S_) && (start < end);
  const int lo = valid ? (start < 0 ? 0 : start) : 0;
  const int hi = valid ? end : 0;

  for (int hh = 0; hh < 4; ++hh) {
    const int h = wid * 4 + hh;
    const short* qp = Q + (size_t)bp * D_ + h * HD_ + dg * 16;
    const short8 q0 = *(const short8*)qp;
    const short8 q1 = *(const short8*)(qp + 8);
    float qf[16];
    #pragma unroll
    for (int j = 0; j < 8; ++j) { qf[j] = b2f(q0[j]); qf[8 + j] = b2f(q1[j]); }

    float mrun = -3.0e38f, denom = 0.f, oacc = 0.f;
    for (int c0 = lo; c0 < hi; c0 += 16) {
      const int t = c0 + tq;
      const bool ok = (t < hi) && (mask[(size_t)b * S_ + t] != 0.f);
      float part = 0.f;
      if (ok) {
        const short* kp = K + ((size_t)b * S_ + t) * D_ + h * HD_ + dg * 16;
        const short8 k0 = *(const short8*)kp;
        const short8 k1 = *(const short8*)(kp + 8);
        #pragma unroll
        for (int j = 0; j < 8; ++j) part += qf[j] * b2f(k0[j]);
        #pragma unroll
        for (int j = 0; j < 8; ++j) part += qf[8 + j] * b2f(k1[j]);
      }
      part += __shfl_xor(part, 16, 64);
      part += __shfl_xor(part, 32, 64);
      const float sc = ok ? part * 0.125f : -3.0e38f;
      float cm = sc;
      cm = fmaxf(cm, __shfl_xor(cm, 1, 64));
      cm = fmaxf(cm, __shfl_xor(cm, 2, 64));
      cm = fmaxf(cm, __shfl_xor(cm, 4, 64));
      cm = fmaxf(cm, __shfl_xor(cm, 8, 64));
      const float nm = fmaxf(mrun, cm);
      if (nm <= -1.0e38f) continue;
      const float r = __expf(mrun - nm);
      const float w = ok ? __expf(sc - nm) : 0.f;
      float ws = w;
      ws += __shfl_xor(ws, 1, 64);
      ws += __shfl_xor(ws, 2, 64);
      ws += __shfl_xor(ws, 4, 64);
      ws += __shfl_xor(ws, 8, 64);
      denom = denom * r + ws;
      oacc *= r;
      #pragma unroll
      for (int k2 = 0; k2 < 16; ++k2) {
        const float wk = __shfl(w, k2, 64);
        if (wk > 0.f) {
          oacc += wk * b2f(V[((size_t)b * S_ + c0 + k2) * D_ + h * HD_ + lane]);
        }
      }
      mrun = nm;
    }
    float res;
    if (denom > 0.f) {
      res = oacc / denom;
    } else {
      float sum = 0.f;
      for (int s0 = 0; s0 < S_; ++s0)
        sum += b2f(V[((size_t)b * S_ + s0) * D_ + h * HD_ + lane]);
      res = sum * (1.0f / S_);
    }
    O[(size_t)bp * D_ + h * HD_ + lane] = f2bf(res);
  }
}

// ---------------------------------------------------------------------------
extern "C" void kernel_launch(void* const* d_in, const int* in_sizes, int n_in,
                              void* d_out, int out_size, void* d_ws, size_t ws_size,
                              hipStream_t stream)
{
  const float* pe    = (const float*)d_in[0];
  const float* xby   = (const float*)d_in[1];
  const int*   pos   = (const int*)d_in[2];
  const float* mask  = (const float*)d_in[3];
  const float* gamma = (const float*)d_in[4];
  const float* beta  = (const float*)d_in[5];
  const float* w_q   = (const float*)d_in[6];
  const float* b_q   = (const float*)d_in[7];
  const float* w_k   = (const float*)d_in[8];
  const float* b_k   = (const float*)d_in[9];
  const float* w_v   = (const float*)d_in[10];
  const float* b_v   = (const float*)d_in[11];
  const float* w_o   = (const float*)d_in[12];
  const float* b_o   = (const float*)d_in[13];

  char* ws = (char*)d_ws;
  short* Xb  = (short*)(ws);                 // 32 MB: byte_hidden bf16 [16384][1024]
  short* Ko  = (short*)(ws + 33554432);      // 32 MB
  short* Vo  = (short*)(ws + 67108864);      // 32 MB
  short* wqb = (short*)(ws + 100663296);     // 2 MB each
  short* wkb = (short*)(ws + 102760448);
  short* wvb = (short*)(ws + 104857600);
  short* wob = (short*)(ws + 106954752);
  short* qx  = (short*)(ws + 109051904);
  short* Qo  = (short*)(ws + 111149056);
  short* AO  = (short*)(ws + 113246208);
  (void)in_sizes; (void)n_in; (void)out_size; (void)ws_size;

  prep_kernel<<<11264, 256, 0, stream>>>(xby, pe, gamma, beta, w_q, w_k, w_v, w_o,
                                         Xb, wqb, wkb, wvb, wob, qx);
  gemm_kvq256<<<528, 512, 0, stream>>>(Xb, qx, wqb, wkb, wvb, b_q, b_k, b_v, Ko, Vo, Qo);
  attn_kernel<<<1024, 256, 0, stream>>>(Qo, Ko, Vo, pos, mask, AO);
  gemm_o<<<64, 256, 0, stream>>>(AO, wob, b_o, pe, (float*)d_out);
}